// Round 4
// baseline (124.351 us; speedup 1.0000x reference)
//
#include <hip/hip_runtime.h>
#include <math.h>

#define BB 8
#define NN 1000
#define CC 81
#define NC 80                     // foreground classes
#define IMG_W_M1 1332.0f
#define IMG_H_M1 799.0f
#define SCORE_THRESH 0.05f
#define NMS_THRESH 0.5f
#define DETS 100
#define CAP 8192                  // per-image candidate capacity after NMS
#define DW_CLIP 4.135166556742356f  // log(1000/16) rounded to f32
#define NBINS 4096
#define SELCAP 1024

// ws layout (bytes):
//   [0, 64)                       u32[16]: [0..7] survivor counts, [8..15] done-block counts
//   [64, 64 + 80*8000*4)          probT: [80][8000] foreground probs, class-major
//   [2560064, 2560064+8*CAP*32)   candidates: per image, CAP x 32B record:
//                                 {x1,y1,x2,y2, score, flatidx(int), pad, pad}
//
// Structure notes (measured across rounds):
//  - R1: fusing topk with __threadfence() in all 640 blocks = +26us
//    (threadfence lowers to s_waitcnt vmcnt(0) + buffer_wbl2 full-L2 writeback).
//  - R4: fuse instead via agent-scope (sc1) atomic stores for candidate records
//    + one inline s_waitcnt vmcnt(0) + device-scope done-counter atomicAdd.
//    sc1 ops are routed through the coherent point (same path that makes plain
//    cross-XCD atomicAdd work), so NO cache writeback/invalidate is needed.
//    Last-arriving block per image runs the top-K; no spinning, no deadlock.
//  - NMS resolve is ballot-form greedy (R2/R3): shfls broadcast ORIGINAL boxes,
//    the only serial dep is a 1-op update of a wave-uniform 64-bit alive mask.

__device__ __forceinline__ unsigned long long pack_ff(float a, float b) {
  return (unsigned long long)__float_as_uint(a) |
         ((unsigned long long)__float_as_uint(b) << 32);
}
__device__ __forceinline__ unsigned long long pack_fi(float a, int b) {
  return (unsigned long long)__float_as_uint(a) |
         ((unsigned long long)(unsigned)b << 32);
}
__device__ __forceinline__ void st_agent_u64(float* p, unsigned long long v) {
  __hip_atomic_store((unsigned long long*)p, v, __ATOMIC_RELAXED,
                     __HIP_MEMORY_SCOPE_AGENT);
}
__device__ __forceinline__ unsigned long long ld_agent_u64(const float* p) {
  return __hip_atomic_load((unsigned long long*)p, __ATOMIC_RELAXED,
                           __HIP_MEMORY_SCOPE_AGENT);
}

// Kernel 1: per-row softmax, written TRANSPOSED so kernel 2 reads coalesced.
// Math is bit-identical to the reference path: serial fmax over c=0..80,
// serial sum of expf in the same order, IEEE divide.
__global__ __launch_bounds__(64) void softmax_probs(
    const float* __restrict__ logits, float* __restrict__ probT,
    unsigned* __restrict__ counters) {
#pragma clang fp contract(off)
  if (blockIdx.x == 0 && threadIdx.x < 16) counters[threadIdx.x] = 0u;
  int r = blockIdx.x * 64 + threadIdx.x;
  if (r >= BB * NN) return;
  const float* l = logits + (size_t)r * CC;
  float m = l[0];
#pragma unroll
  for (int c = 1; c < CC; ++c) m = fmaxf(m, l[c]);
  float e[CC];
  float s = 0.0f;
#pragma unroll
  for (int c = 0; c < CC; ++c) { e[c] = expf(l[c] - m); s += e[c]; }
  // transposed store: for fixed c, lanes write 64 consecutive floats.
#pragma unroll
  for (int c = 1; c < CC; ++c)
    probT[(size_t)(c - 1) * (BB * NN) + r] = e[c] / s;
}

// Kernel 2: per-(image,class) filter + sort + decode + greedy NMS; the LAST
// block to publish for an image runs the per-image top-K inline.
__global__ __launch_bounds__(256) void per_class_nms_topk(
    const float* __restrict__ probT, const float* __restrict__ reg,
    const float* __restrict__ props, unsigned* __restrict__ counters,
    float* __restrict__ cand, float* __restrict__ dets_out,
    float* __restrict__ labels_out) {
#pragma clang fp contract(off)
  // 33 KB overlay: NMS-phase arrays and topk-phase arrays never live at the
  // same time (topk runs only after the final barrier in the last block).
  __shared__ __align__(16) char smem[33024];
  float*         s_score  = (float*)(smem);          //  4000 B
  int*           s_idx    = (int*)(smem + 4000);     //  4000 B
  float*         s_sscore = (float*)(smem + 8000);   //  4000 B
  int*           s_sidx   = (int*)(smem + 12000);    //  4000 B
  float*         s_box    = (float*)(smem + 16000);  // 16000 B
  unsigned char* s_keep   = (unsigned char*)(smem + 32000);  // 1000 B
  __shared__ unsigned s_pref[17];
  __shared__ int s_cnt;
  __shared__ unsigned s_base;
  __shared__ int s_last, s_m, s_cut;

  const int img = blockIdx.x / NC;
  const int cls = blockIdx.x % NC + 1;   // foreground class id 1..80
  const int t = threadIdx.x;
  const int lane = t & 63;
  const int wv = t >> 6;

  if (t == 0) s_cnt = 0;
  __syncthreads();

  // Phase 1: collect candidates with prob > thresh — coalesced column read,
  // no expf (precomputed in kernel 1, bitwise-identical values).
  const float* pcol = probT + (size_t)(cls - 1) * (BB * NN) + img * NN;
  for (int r = t; r < NN; r += 256) {
    float p = pcol[r];
    if (p > SCORE_THRESH) {
      int pos = atomicAdd(&s_cnt, 1);
      s_score[pos] = p;
      s_idx[pos] = r;
    }
  }
  __syncthreads();
  const int n = s_cnt;

  // Phase 2: rank sort by (score desc, original row asc) == stable argsort(-scores)
  for (int i = t; i < n; i += 256) {
    float si = s_score[i];
    int   ii = s_idx[i];
    int rank = 0;
#pragma unroll 8
    for (int j = 0; j < n; ++j) {
      float sj = s_score[j];
      rank += (int)((sj > si) | ((sj == si) & (s_idx[j] < ii)));
    }
    s_sscore[rank] = si;
    s_sidx[rank] = ii;
  }
  __syncthreads();

  // Phase 3: decode + clip boxes for sorted candidates (BoxCoder.decode, TO_REMOVE=1)
  for (int i = t; i < n; i += 256) {
    int r = s_sidx[i];
    int row = img * NN + r;
    const float4 pv = *reinterpret_cast<const float4*>(props + (size_t)row * 4);
    float w = pv.z - pv.x + 1.0f, h = pv.w - pv.y + 1.0f;
    float cx = pv.x + 0.5f * w,  cy = pv.y + 0.5f * h;
    const float4 rv = *reinterpret_cast<const float4*>(reg + (size_t)row * (CC * 4) + cls * 4);
    float dx = rv.x / 10.0f, dy = rv.y / 10.0f;
    float dw = fminf(rv.z / 5.0f, DW_CLIP);
    float dh = fminf(rv.w / 5.0f, DW_CLIP);
    float pcx = dx * w + cx, pcy = dy * h + cy;
    float pw = expf(dw) * w, ph = expf(dh) * h;
    float bx1 = pcx - 0.5f * pw;
    float by1 = pcy - 0.5f * ph;
    float bx2 = pcx + 0.5f * pw - 1.0f;
    float by2 = pcy + 0.5f * ph - 1.0f;
    bx1 = fminf(fmaxf(bx1, 0.0f), IMG_W_M1);
    bx2 = fminf(fmaxf(bx2, 0.0f), IMG_W_M1);
    by1 = fminf(fmaxf(by1, 0.0f), IMG_H_M1);
    by2 = fminf(fmaxf(by2, 0.0f), IMG_H_M1);
    s_box[i * 4 + 0] = bx1;
    s_box[i * 4 + 1] = by1;
    s_box[i * 4 + 2] = bx2;
    s_box[i * 4 + 3] = by2;
    s_keep[i] = 1;
  }
  __syncthreads();

  // Phase 4: greedy NMS, chunk-synchronous, ballot-form resolve (== sequential
  // greedy; see structure notes).
  const int nch = (n + 63) >> 6;
  for (int c0 = 0; c0 < nch; ++c0) {
    const int i0 = c0 << 6;
    if (t < 64) {
      const int i = i0 + t;
      const bool has = (i < n);
      float bx1 = 0.f, by1 = 0.f, bx2 = 0.f, by2 = 0.f, areaB = 0.f;
      bool kp0 = false;
      if (has) {
        kp0 = (s_keep[i] != 0);
        bx1 = s_box[i * 4 + 0]; by1 = s_box[i * 4 + 1];
        bx2 = s_box[i * 4 + 2]; by2 = s_box[i * 4 + 3];
        areaB = (bx2 - bx1) * (by2 - by1);
      }
      unsigned long long alive = __ballot(kp0);
      for (int l = 0; l < 64; ++l) {
        float ax1 = __shfl(bx1, l), ay1 = __shfl(by1, l);
        float ax2 = __shfl(bx2, l), ay2 = __shfl(by2, l);
        float areaA = __shfl(areaB, l);
        float wx = fmaxf(fminf(ax2, bx2) - fmaxf(ax1, bx1), 0.0f);
        float wy = fmaxf(fminf(ay2, by2) - fmaxf(ay1, by1), 0.0f);
        float inter = wx * wy;
        float iou = inter / ((areaA + areaB) - inter + 1e-9f);
        unsigned long long bal = __ballot((iou > NMS_THRESH) && (t > l));
        if ((alive >> l) & 1ull) alive &= ~bal;
      }
      if (has) s_keep[i] = (unsigned char)((alive >> t) & 1ull);
    }
    __syncthreads();
    const int jbeg = i0 + 64;
    if (jbeg < n) {
      const int kmax = (n - i0 < 64) ? (n - i0) : 64;
      for (int j = jbeg + t; j < n; j += 256) {
        if (!s_keep[j]) continue;
        float bx1 = s_box[j * 4 + 0], by1 = s_box[j * 4 + 1];
        float bx2 = s_box[j * 4 + 2], by2 = s_box[j * 4 + 3];
        float areaB = (bx2 - bx1) * (by2 - by1);
        unsigned char f = 1;
        for (int k = 0; k < kmax; ++k) {
          if (!s_keep[i0 + k]) continue;          // uniform LDS broadcast
          float ax1 = s_box[(i0 + k) * 4 + 0], ay1 = s_box[(i0 + k) * 4 + 1];
          float ax2 = s_box[(i0 + k) * 4 + 2], ay2 = s_box[(i0 + k) * 4 + 3];
          float areaA = (ax2 - ax1) * (ay2 - ay1);
          float wx = fmaxf(fminf(ax2, bx2) - fmaxf(ax1, bx1), 0.0f);
          float wy = fmaxf(fminf(ay2, by2) - fmaxf(ay1, by1), 0.0f);
          float inter = wx * wy;
          float iou = inter / ((areaA + areaB) - inter + 1e-9f);
          if (iou > NMS_THRESH) { f = 0; break; }
        }
        if (!f) s_keep[j] = 0;
      }
    }
    __syncthreads();
  }

  // Phase 5: emit survivors via agent-scope (sc1) stores — coherent-point
  // writes, visible to the reader block without any cache flush.
  for (int c = wv; c < 16; c += 4) {
    unsigned long long mask = 0ull;
    if (c < nch) {
      int i = (c << 6) + lane;
      mask = __ballot((i < n) && s_keep[i]);
    }
    if (lane == 0) s_pref[c] = (unsigned)__popcll(mask);
  }
  __syncthreads();
  if (t == 0) {
    unsigned run = 0;
#pragma unroll
    for (int c = 0; c < 16; ++c) { unsigned v = s_pref[c]; s_pref[c] = run; run += v; }
    s_base = (run > 0) ? atomicAdd(&counters[img], run) : 0u;
  }
  __syncthreads();
  for (int c = wv; c < nch; c += 4) {
    int i = (c << 6) + lane;
    bool kp = (i < n) && s_keep[i];
    unsigned long long mask = __ballot(kp);
    if (kp) {
      unsigned pos = s_pref[c] + (unsigned)__popcll(mask & ((1ull << lane) - 1ull));
      unsigned gpos = s_base + pos;
      if (gpos < CAP) {
        float* crec = cand + ((size_t)img * CAP + gpos) * 8;
        st_agent_u64(crec + 0, pack_ff(s_box[i * 4 + 0], s_box[i * 4 + 1]));
        st_agent_u64(crec + 2, pack_ff(s_box[i * 4 + 2], s_box[i * 4 + 3]));
        st_agent_u64(crec + 4, pack_fi(s_sscore[i], (cls - 1) * NN + s_sidx[i]));
      }
    }
  }

  // Publication: drain our sc1 stores + the survivor-count atomic (vmcnt
  // retirement of sc1 ops => agent-visible), barrier so ALL threads' stores
  // are covered, then one done-add. The block seeing NC-1 is the reader.
  asm volatile("s_waitcnt vmcnt(0)" ::: "memory");
  __syncthreads();
  if (t == 0) {
    unsigned d = atomicAdd(&counters[8 + img], 1u);
    s_last = (d == (unsigned)(NC - 1)) ? 1 : 0;
  }
  __syncthreads();
  if (!s_last) return;          // uniform: s_last is shared

  // ---- Fused per-image top-K (exactly one block per image; overlaps with
  //      other images' NMS blocks still in flight) ----
  unsigned* hist  = (unsigned*)(smem);          // 16384 B (overlays NMS arrays)
  float*    s_ssc = (float*)(smem + 16384);     //  4096 B
  int*      s_sfl = (int*)(smem + 20480);       //  4096 B
  int*      s_sci = (int*)(smem + 24576);       //  4096 B

  int n2 = (int)__hip_atomic_load(&counters[img], __ATOMIC_RELAXED,
                                  __HIP_MEMORY_SCOPE_AGENT);
  if (n2 > CAP) n2 = CAP;
  const int K = (n2 < DETS) ? n2 : DETS;
  const float* cbase = cand + (size_t)img * CAP * 8;
  float* dbase = dets_out + (size_t)img * DETS * 5;

  if (t == 0) { s_m = 0; s_cut = 0; }
  for (int k = t; k < DETS; k += 256) {
    if (k >= K) {   // ranks 0..K-1 each written exactly once below
      float* d = dbase + (size_t)k * 5;
      d[0] = 0.0f; d[1] = 0.0f; d[2] = 0.0f; d[3] = 0.0f; d[4] = 0.0f;
      labels_out[img * DETS + k] = -1.0f;
    }
  }
  for (int b = t; b < NBINS; b += 256) hist[b] = 0u;
  __syncthreads();

  // Histogram of scores. bin = floor(score*4096) is monotone in score, so
  // {bin >= cut} is upward-closed: it contains the exact global top-K, and
  // within-set ranks equal global ranks.
  if (K > 0) {
    for (int i = t; i < n2; i += 256) {
      unsigned long long v = ld_agent_u64(cbase + i * 8 + 4);
      float sc = __uint_as_float((unsigned)v);
      int bin = (int)(sc * (float)NBINS);
      if (bin > NBINS - 1) bin = NBINS - 1;
      atomicAdd(&hist[bin], 1u);
    }
  }
  __syncthreads();

  // Wave 0: find largest cutoff bin T with count(bin >= T) >= K.
  if (t < 64 && K > 0) {
    unsigned s = 0;
#pragma unroll
    for (int b = 0; b < 64; ++b) s += hist[t * 64 + b];
    unsigned suf = s;                       // suffix-inclusive scan over 64 superbins
    for (int d = 1; d < 64; d <<= 1) {
      unsigned o = __shfl_down(suf, d);
      if (t + d < 64) suf += o;
    }
    unsigned long long m1 = __ballot(suf >= (unsigned)K);
    int S = 63 - __clzll(m1);               // largest superbin with suffix >= K
    unsigned tail = 0;
    if (S < 63) tail = __shfl(suf, S + 1);  // S uniform across wave
    unsigned h = hist[S * 64 + t];
    unsigned suf2 = h;
    for (int d = 1; d < 64; d <<= 1) {
      unsigned o = __shfl_down(suf2, d);
      if (t + d < 64) suf2 += o;
    }
    unsigned long long m2 = __ballot((suf2 + tail) >= (unsigned)K);
    int Ls = 63 - __clzll(m2);
    if (t == 0) s_cut = S * 64 + Ls;
  }
  __syncthreads();
  const int cut = s_cut;

  // Select candidates with bin >= cut into compact list.
  if (K > 0) {
    for (int i = t; i < n2; i += 256) {
      unsigned long long v = ld_agent_u64(cbase + i * 8 + 4);
      float sc = __uint_as_float((unsigned)v);
      int bin = (int)(sc * (float)NBINS);
      if (bin > NBINS - 1) bin = NBINS - 1;
      if (bin >= cut) {
        int p = atomicAdd(&s_m, 1);
        if (p < SELCAP) {
          s_ssc[p] = sc;
          s_sfl[p] = (int)(unsigned)(v >> 32);
          s_sci[p] = i;
        }
      }
    }
  }
  __syncthreads();
  const int m = s_m;

  if (m <= SELCAP) {
    // Exact rank among selected == global rank. O(m^2), m ~ 100-300.
    for (int i = t; i < m; i += 256) {
      float si = s_ssc[i];
      int   fi = s_sfl[i];
      int rank = 0;
#pragma unroll 4
      for (int j = 0; j < m; ++j) {
        float sj = s_ssc[j];
        rank += (int)((sj > si) | ((sj == si) & (s_sfl[j] < fi)));
      }
      if (rank < DETS) {
        int ci = s_sci[i];
        unsigned long long b01 = ld_agent_u64(cbase + ci * 8 + 0);
        unsigned long long b23 = ld_agent_u64(cbase + ci * 8 + 2);
        float* d = dbase + (size_t)rank * 5;
        d[0] = __uint_as_float((unsigned)b01);
        d[1] = __uint_as_float((unsigned)(b01 >> 32));
        d[2] = __uint_as_float((unsigned)b23);
        d[3] = __uint_as_float((unsigned)(b23 >> 32));
        d[4] = si;
        labels_out[img * DETS + rank] = (float)(fi / NN + 1);
      }
    }
  } else {
    // Fallback (mass-tie pathology, never hit on real data): exact O(n^2) rank.
    for (int i = t; i < n2; i += 256) {
      unsigned long long vi = ld_agent_u64(cbase + i * 8 + 4);
      float si = __uint_as_float((unsigned)vi);
      int   fi = (int)(unsigned)(vi >> 32);
      int rank = 0;
      for (int j = 0; j < n2; ++j) {
        unsigned long long vj = ld_agent_u64(cbase + j * 8 + 4);
        float sj = __uint_as_float((unsigned)vj);
        int   fj = (int)(unsigned)(vj >> 32);
        rank += (int)((sj > si) | ((sj == si) & (fj < fi)));
      }
      if (rank < DETS) {
        unsigned long long b01 = ld_agent_u64(cbase + i * 8 + 0);
        unsigned long long b23 = ld_agent_u64(cbase + i * 8 + 2);
        float* d = dbase + (size_t)rank * 5;
        d[0] = __uint_as_float((unsigned)b01);
        d[1] = __uint_as_float((unsigned)(b01 >> 32));
        d[2] = __uint_as_float((unsigned)b23);
        d[3] = __uint_as_float((unsigned)(b23 >> 32));
        d[4] = si;
        labels_out[img * DETS + rank] = (float)(fi / NN + 1);
      }
    }
  }
}

extern "C" void kernel_launch(void* const* d_in, const int* in_sizes, int n_in,
                              void* d_out, int out_size, void* d_ws, size_t ws_size,
                              hipStream_t stream) {
  const float* logits = (const float*)d_in[0];   // [8000, 81]
  const float* reg    = (const float*)d_in[1];   // [8000, 324]
  const float* props  = (const float*)d_in[2];   // [8000, 4]
  // d_in[3] = features, unused (OUTPUT_FEATURE=False)

  float* out = (float*)d_out;                    // dets [8,100,5] then labels [8,100]
  char* ws = (char*)d_ws;
  unsigned* counters = (unsigned*)(ws);                  // u32[16]
  float*    probT    = (float*)(ws + 64);                // [80][8000]
  float*    cand     = (float*)(ws + 64 + 2560000);      // [8][CAP][8]

  softmax_probs<<<(BB * NN + 63) / 64, 64, 0, stream>>>(logits, probT, counters);
  per_class_nms_topk<<<BB * NC, 256, 0, stream>>>(probT, reg, props, counters,
                                                  cand, out, out + BB * DETS * 5);
}

// Round 5
// 117.707 us; speedup vs baseline: 1.0564x; 1.0564x over previous
//
#include <hip/hip_runtime.h>
#include <math.h>

#define BB 8
#define NN 1000
#define CC 81
#define NC 80                     // foreground classes
#define IMG_W_M1 1332.0f
#define IMG_H_M1 799.0f
#define SCORE_THRESH 0.05f
#define NMS_THRESH 0.5f
#define DETS 100
#define CAP 8192                  // per-image candidate capacity after NMS
#define DW_CLIP 4.135166556742356f  // log(1000/16) rounded to f32
#define NBINS 4096
#define SELCAP 1024

// ws layout (bytes):
//   [0, 64)                       u32[16]: counters[0..7] = survivor counts
//   [64, 64 + 80*8000*4)          probT: [80][8000] foreground probs, class-major
//   [2560064, 2560064+8*CAP*32)   candidates: per image, CAP x 32B record:
//                                 {x1,y1,x2,y2, score, flatidx(int), pad, pad}
//
// Structure notes (measured across rounds):
//  - 3 separate launches ON PURPOSE. Fusing topk into the NMS kernel loses both
//    ways: __threadfence in 640 blocks = +26us (R1, buffer_wbl2 L2 writeback);
//    sc1 agent-scope publication = fused kernel 52us of which ~35us is a
//    low-occupancy tail of uncached candidate reads in 8 blocks (R4, 124.4us
//    total vs 118.5 for 3-launch). Kernel boundaries give cache-warm topk reads.
//  - NMS resolve is ballot-form greedy: shfls broadcast ORIGINAL boxes
//    (independent per iteration -> pipelined); only serial dep is a 1-op update
//    of a wave-uniform 64-bit alive mask. == sequential greedy exactly.
//  - Rank-sort and decode are MERGED: ranks are unique, so each thread computes
//    its rank and writes score/idx/box at the rank slot; the scattered
//    props/reg gathers (longest-latency event per block) issue before the rank
//    loop and retire under it. Same FP ops, same order -> bit-identical.

// Kernel 1: per-row softmax, written TRANSPOSED so kernel 2 reads coalesced.
// Math is bit-identical to the reference path: serial fmax over c=0..80,
// serial sum of expf in the same order, IEEE divide.
__global__ __launch_bounds__(64) void softmax_probs(
    const float* __restrict__ logits, float* __restrict__ probT,
    unsigned* __restrict__ counters) {
#pragma clang fp contract(off)
  if (blockIdx.x == 0 && threadIdx.x < 16) counters[threadIdx.x] = 0u;
  int r = blockIdx.x * 64 + threadIdx.x;
  if (r >= BB * NN) return;
  const float* l = logits + (size_t)r * CC;
  float m = l[0];
#pragma unroll
  for (int c = 1; c < CC; ++c) m = fmaxf(m, l[c]);
  float e[CC];
  float s = 0.0f;
#pragma unroll
  for (int c = 0; c < CC; ++c) { e[c] = expf(l[c] - m); s += e[c]; }
  // transposed store: for fixed c, lanes write 64 consecutive floats.
#pragma unroll
  for (int c = 1; c < CC; ++c)
    probT[(size_t)(c - 1) * (BB * NN) + r] = e[c] / s;
}

// Kernel 2: per-(image,class) candidate filter + sort+decode + greedy NMS.
__global__ __launch_bounds__(256) void per_class_nms(
    const float* __restrict__ probT, const float* __restrict__ reg,
    const float* __restrict__ props, unsigned* __restrict__ counters,
    float* __restrict__ cand) {
#pragma clang fp contract(off)
  __shared__ float s_score[NN];
  __shared__ int   s_idx[NN];
  __shared__ float s_sscore[NN];
  __shared__ int   s_sidx[NN];
  __shared__ float s_box[NN * 4];
  __shared__ unsigned char s_keep[NN];
  __shared__ unsigned s_pref[17];
  __shared__ int s_cnt;
  __shared__ unsigned s_base;

  const int img = blockIdx.x / NC;
  const int cls = blockIdx.x % NC + 1;   // foreground class id 1..80
  const int t = threadIdx.x;
  const int lane = t & 63;
  const int wv = t >> 6;

  if (t == 0) s_cnt = 0;
  __syncthreads();

  // Phase 1: collect candidates with prob > thresh — coalesced column read,
  // no expf (precomputed in kernel 1, bitwise-identical values).
  const float* pcol = probT + (size_t)(cls - 1) * (BB * NN) + img * NN;
  for (int r = t; r < NN; r += 256) {
    float p = pcol[r];
    if (p > SCORE_THRESH) {
      int pos = atomicAdd(&s_cnt, 1);
      s_score[pos] = p;
      s_idx[pos] = r;
    }
  }
  __syncthreads();
  const int n = s_cnt;

  // Phase 2 (merged rank-sort + decode): for each unsorted candidate, issue the
  // scattered props/reg loads FIRST (independent of the rank loop), compute the
  // stable rank (score desc, original row asc) from LDS while the gathers are
  // in flight, then decode+clip and write everything at the rank slot.
  for (int i = t; i < n; i += 256) {
    const float si = s_score[i];
    const int   r  = s_idx[i];
    const int row = img * NN + r;
    const float4 pv = *reinterpret_cast<const float4*>(props + (size_t)row * 4);
    // reg row base = row*1296B + cls*16B -> 16B aligned
    const float4 rv = *reinterpret_cast<const float4*>(reg + (size_t)row * (CC * 4) + cls * 4);

    int rank = 0;
#pragma unroll 8
    for (int j = 0; j < n; ++j) {
      float sj = s_score[j];
      rank += (int)((sj > si) | ((sj == si) & (s_idx[j] < r)));
    }

    // BoxCoder.decode (TO_REMOVE=1) + clip — identical ops/order to reference.
    float w = pv.z - pv.x + 1.0f, h = pv.w - pv.y + 1.0f;
    float cx = pv.x + 0.5f * w,  cy = pv.y + 0.5f * h;
    float dx = rv.x / 10.0f, dy = rv.y / 10.0f;
    float dw = fminf(rv.z / 5.0f, DW_CLIP);
    float dh = fminf(rv.w / 5.0f, DW_CLIP);
    float pcx = dx * w + cx, pcy = dy * h + cy;
    float pw = expf(dw) * w, ph = expf(dh) * h;
    float bx1 = pcx - 0.5f * pw;
    float by1 = pcy - 0.5f * ph;
    float bx2 = pcx + 0.5f * pw - 1.0f;
    float by2 = pcy + 0.5f * ph - 1.0f;
    bx1 = fminf(fmaxf(bx1, 0.0f), IMG_W_M1);
    bx2 = fminf(fmaxf(bx2, 0.0f), IMG_W_M1);
    by1 = fminf(fmaxf(by1, 0.0f), IMG_H_M1);
    by2 = fminf(fmaxf(by2, 0.0f), IMG_H_M1);

    s_sscore[rank] = si;           // ranks are unique: each slot written once
    s_sidx[rank] = r;
    s_box[rank * 4 + 0] = bx1;
    s_box[rank * 4 + 1] = by1;
    s_box[rank * 4 + 2] = bx2;
    s_box[rank * 4 + 3] = by2;
    s_keep[rank] = 1;
  }
  __syncthreads();

  // Phase 4: greedy NMS, chunk-synchronous, ballot-form resolve (== sequential
  // greedy; see structure notes).
  const int nch = (n + 63) >> 6;
  for (int c0 = 0; c0 < nch; ++c0) {
    const int i0 = c0 << 6;
    if (t < 64) {
      const int i = i0 + t;
      const bool has = (i < n);
      float bx1 = 0.f, by1 = 0.f, bx2 = 0.f, by2 = 0.f, areaB = 0.f;
      bool kp0 = false;
      if (has) {
        kp0 = (s_keep[i] != 0);
        bx1 = s_box[i * 4 + 0]; by1 = s_box[i * 4 + 1];
        bx2 = s_box[i * 4 + 2]; by2 = s_box[i * 4 + 3];
        areaB = (bx2 - bx1) * (by2 - by1);
      }
      unsigned long long alive = __ballot(kp0);
      for (int l = 0; l < 64; ++l) {
        float ax1 = __shfl(bx1, l), ay1 = __shfl(by1, l);
        float ax2 = __shfl(bx2, l), ay2 = __shfl(by2, l);
        float areaA = __shfl(areaB, l);
        float wx = fmaxf(fminf(ax2, bx2) - fmaxf(ax1, bx1), 0.0f);
        float wy = fmaxf(fminf(ay2, by2) - fmaxf(ay1, by1), 0.0f);
        float inter = wx * wy;
        float iou = inter / ((areaA + areaB) - inter + 1e-9f);
        unsigned long long bal = __ballot((iou > NMS_THRESH) && (t > l));
        if ((alive >> l) & 1ull) alive &= ~bal;
      }
      if (has) s_keep[i] = (unsigned char)((alive >> t) & 1ull);
    }
    __syncthreads();
    const int jbeg = i0 + 64;
    if (jbeg < n) {
      const int kmax = (n - i0 < 64) ? (n - i0) : 64;
      for (int j = jbeg + t; j < n; j += 256) {
        if (!s_keep[j]) continue;
        float bx1 = s_box[j * 4 + 0], by1 = s_box[j * 4 + 1];
        float bx2 = s_box[j * 4 + 2], by2 = s_box[j * 4 + 3];
        float areaB = (bx2 - bx1) * (by2 - by1);
        unsigned char f = 1;
        for (int k = 0; k < kmax; ++k) {
          if (!s_keep[i0 + k]) continue;          // uniform LDS broadcast
          float ax1 = s_box[(i0 + k) * 4 + 0], ay1 = s_box[(i0 + k) * 4 + 1];
          float ax2 = s_box[(i0 + k) * 4 + 2], ay2 = s_box[(i0 + k) * 4 + 3];
          float areaA = (ax2 - ax1) * (ay2 - ay1);
          float wx = fmaxf(fminf(ax2, bx2) - fmaxf(ax1, bx1), 0.0f);
          float wy = fmaxf(fminf(ay2, by2) - fmaxf(ay1, by1), 0.0f);
          float inter = wx * wy;
          float iou = inter / ((areaA + areaB) - inter + 1e-9f);
          if (iou > NMS_THRESH) { f = 0; break; }
        }
        if (!f) s_keep[j] = 0;
      }
    }
    __syncthreads();
  }

  // Phase 5: emit survivors. Ballot-based compaction: per-64-chunk masks +
  // 16-entry prefix; plain (cached) stores — next kernel boundary publishes.
  for (int c = wv; c < 16; c += 4) {
    unsigned long long mask = 0ull;
    if (c < nch) {
      int i = (c << 6) + lane;
      mask = __ballot((i < n) && s_keep[i]);
    }
    if (lane == 0) s_pref[c] = (unsigned)__popcll(mask);
  }
  __syncthreads();
  if (t == 0) {
    unsigned run = 0;
#pragma unroll
    for (int c = 0; c < 16; ++c) { unsigned v = s_pref[c]; s_pref[c] = run; run += v; }
    s_base = (run > 0) ? atomicAdd(&counters[img], run) : 0u;
  }
  __syncthreads();
  for (int c = wv; c < nch; c += 4) {
    int i = (c << 6) + lane;
    bool kp = (i < n) && s_keep[i];
    unsigned long long mask = __ballot(kp);
    if (kp) {
      unsigned pos = s_pref[c] + (unsigned)__popcll(mask & ((1ull << lane) - 1ull));
      unsigned gpos = s_base + pos;
      if (gpos < CAP) {
        float* crec = cand + ((size_t)img * CAP + gpos) * 8;
        float4 bx;
        bx.x = s_box[i * 4 + 0]; bx.y = s_box[i * 4 + 1];
        bx.z = s_box[i * 4 + 2]; bx.w = s_box[i * 4 + 3];
        *reinterpret_cast<float4*>(crec) = bx;          // 32B-aligned record
        crec[4] = s_sscore[i];
        ((int*)crec)[5] = (cls - 1) * NN + s_sidx[i];   // flat idx: tie-break + label
      }
    }
  }
}

#define TK_THREADS 1024

__global__ __launch_bounds__(TK_THREADS) void topk_out(
    const unsigned* __restrict__ counters, const float* __restrict__ cand,
    float* __restrict__ dets_out, float* __restrict__ labels_out) {
#pragma clang fp contract(off)
  __shared__ float s_sc[CAP];
  __shared__ int   s_fl[CAP];
  __shared__ unsigned hist[NBINS];
  __shared__ float s_ssc[SELCAP];
  __shared__ int   s_sfl[SELCAP];
  __shared__ int   s_sci[SELCAP];
  __shared__ int s_m, s_cut;

  const int img = blockIdx.x;
  const int t = threadIdx.x;
  int n = (int)counters[img];
  if (n > CAP) n = CAP;
  const int K = (n < DETS) ? n : DETS;
  const float* cbase = cand + (size_t)img * CAP * 8;

  if (t == 0) { s_m = 0; s_cut = 0; }
  for (int b = t; b < NBINS; b += TK_THREADS) hist[b] = 0u;

  for (int i = t; i < n; i += TK_THREADS) {
    s_sc[i] = cbase[i * 8 + 4];
    s_fl[i] = ((const int*)cbase)[i * 8 + 5];
  }
  // Defaults for slots beyond candidate count (ranks 0..K-1 all get written
  // exactly once below, since ranks are unique).
  for (int k = t; k < DETS; k += TK_THREADS) {
    if (k >= K) {
      float* d = dets_out + (size_t)(img * DETS + k) * 5;
      d[0] = 0.0f; d[1] = 0.0f; d[2] = 0.0f; d[3] = 0.0f; d[4] = 0.0f;
      labels_out[img * DETS + k] = -1.0f;
    }
  }
  __syncthreads();

  // Histogram of scores. bin = floor(score*4096) is monotone non-decreasing in
  // score, so {bin >= T} is upward-closed: it contains the exact global top-K,
  // and within-set ranks equal global ranks (excluded => strictly smaller score).
  for (int i = t; i < n; i += TK_THREADS) {
    float sc = s_sc[i];
    int bin = (int)(sc * (float)NBINS);
    if (bin > NBINS - 1) bin = NBINS - 1;
    atomicAdd(&hist[bin], 1u);
  }
  __syncthreads();

  // Wave 0: find largest cutoff bin T with count(bin >= T) >= K.
  if (t < 64 && K > 0) {
    unsigned s = 0;
#pragma unroll
    for (int b = 0; b < 64; ++b) s += hist[t * 64 + b];
    unsigned suf = s;                       // suffix-inclusive scan over 64 superbins
    for (int d = 1; d < 64; d <<= 1) {
      unsigned o = __shfl_down(suf, d);
      if (t + d < 64) suf += o;
    }
    unsigned long long m1 = __ballot(suf >= (unsigned)K);
    int S = 63 - __clzll(m1);               // largest superbin with suffix >= K
    unsigned tail = 0;
    if (S < 63) tail = __shfl(suf, S + 1);  // S uniform across wave
    unsigned h = hist[S * 64 + t];
    unsigned suf2 = h;
    for (int d = 1; d < 64; d <<= 1) {
      unsigned o = __shfl_down(suf2, d);
      if (t + d < 64) suf2 += o;
    }
    unsigned long long m2 = __ballot((suf2 + tail) >= (unsigned)K);
    int Ls = 63 - __clzll(m2);
    if (t == 0) s_cut = S * 64 + Ls;
  }
  __syncthreads();
  const int cut = s_cut;

  // Select candidates with bin >= cut into compact list.
  if (K > 0) {
    for (int i = t; i < n; i += TK_THREADS) {
      float sc = s_sc[i];
      int bin = (int)(sc * (float)NBINS);
      if (bin > NBINS - 1) bin = NBINS - 1;
      if (bin >= cut) {
        int p = atomicAdd(&s_m, 1);
        if (p < SELCAP) { s_ssc[p] = sc; s_sfl[p] = s_fl[i]; s_sci[p] = i; }
      }
    }
  }
  __syncthreads();
  const int m = s_m;

  if (m <= SELCAP) {
    // Exact rank among selected == global rank. O(m^2), m ~ 100-300.
    for (int i = t; i < m; i += TK_THREADS) {
      float si = s_ssc[i];
      int   fi = s_sfl[i];
      int rank = 0;
#pragma unroll 4
      for (int j = 0; j < m; ++j) {
        float sj = s_ssc[j];
        rank += (int)((sj > si) | ((sj == si) & (s_sfl[j] < fi)));
      }
      if (rank < DETS) {
        int ci = s_sci[i];
        const float4 bx = *reinterpret_cast<const float4*>(cbase + ci * 8);
        float* d = dets_out + (size_t)(img * DETS + rank) * 5;
        d[0] = bx.x; d[1] = bx.y; d[2] = bx.z; d[3] = bx.w;
        d[4] = si;
        labels_out[img * DETS + rank] = (float)(fi / NN + 1);
      }
    }
  } else {
    // Fallback (mass-tie pathology, never hit on real data): full O(n^2) rank.
    for (int i = t; i < n; i += TK_THREADS) {
      float si = s_sc[i];
      int   fi = s_fl[i];
      int rank = 0;
#pragma unroll 8
      for (int j = 0; j < n; ++j) {
        float sj = s_sc[j];
        rank += (int)((sj > si) | ((sj == si) & (s_fl[j] < fi)));
      }
      if (rank < DETS) {
        const float4 bx = *reinterpret_cast<const float4*>(cbase + i * 8);
        float* d = dets_out + (size_t)(img * DETS + rank) * 5;
        d[0] = bx.x; d[1] = bx.y; d[2] = bx.z; d[3] = bx.w;
        d[4] = si;
        labels_out[img * DETS + rank] = (float)(fi / NN + 1);
      }
    }
  }
}

extern "C" void kernel_launch(void* const* d_in, const int* in_sizes, int n_in,
                              void* d_out, int out_size, void* d_ws, size_t ws_size,
                              hipStream_t stream) {
  const float* logits = (const float*)d_in[0];   // [8000, 81]
  const float* reg    = (const float*)d_in[1];   // [8000, 324]
  const float* props  = (const float*)d_in[2];   // [8000, 4]
  // d_in[3] = features, unused (OUTPUT_FEATURE=False)

  float* out = (float*)d_out;                    // dets [8,100,5] then labels [8,100]
  char* ws = (char*)d_ws;
  unsigned* counters = (unsigned*)(ws);                  // u32[16]
  float*    probT    = (float*)(ws + 64);                // [80][8000]
  float*    cand     = (float*)(ws + 64 + 2560000);      // [8][CAP][8]

  softmax_probs<<<(BB * NN + 63) / 64, 64, 0, stream>>>(logits, probT, counters);
  per_class_nms<<<BB * NC, 256, 0, stream>>>(probT, reg, props, counters, cand);
  topk_out<<<BB, TK_THREADS, 0, stream>>>(counters, cand, out, out + BB * DETS * 5);
}